// Round 1
// 7497.723 us; speedup vs baseline: 1.2494x; 1.2494x over previous
//
#include <hip/hip_runtime.h>
#include <math.h>

// Sinkhorn OT layer, B=8192, C=256, L=100, LAMBD=1.
//
// U = log_u - ||x_i||^2, V = log_v - ||y_j||^2, G[i][j] = 2*dot(x_i,y_j):
//   U[i] = -LSE_j(G[i][j] + V[j]),  V[j] = -LSE_i(G[i][j] + U[i])
// init V[j] = -||y_j||^2. Final: out[i] = y[argmax_j(G[i][j]+V[j])].
//
// R6: G stored as 24-bit fixed point (q = 2^-15, covers |G|<256, err 1.5e-5
// ~= existing fp32 reduction-order noise) split into Glo (u16, 128 MiB) +
// Ghi (s8, 64 MiB). Per-iteration traffic 512 -> 384 MiB; G footprint
// 192 MiB < 256 MiB Infinity Cache so zigzag traversal can now get real
// L3 hits. LSE/argmax need ABSOLUTE precision -> fixed point, not fp16.
//
// Kept from R3/R5: separate col_partial + col_combine (fused combine with
// ACQ_REL atomics was ~25 us/iter slower), conflict-free GEMM tiles,
// device-global small state (plain loads/stores; visibility via kernel
// boundaries), zigzag traversal (col pass walks rows DESCENDING).

#define B 8192
#define C 256
#define LITERS 100
#define CHUNKS 32
#define RPC 256                    // rows per column-pass chunk

#define QS 65536.0f                // (2*acc) * 32768 == acc * 65536
#define QI 3.0517578125e-5f        // 2^-15

typedef float f32x4 __attribute__((ext_vector_type(4)));
typedef unsigned short u16x8 __attribute__((ext_vector_type(8)));
typedef signed char i8x8 __attribute__((ext_vector_type(8)));

__device__ __align__(16) float g_U[B];
__device__ __align__(16) float g_V[B];
__device__ __align__(16) float g_pm[CHUNKS * B];
__device__ __align__(16) float g_ps[CHUNKS * B];

// ---------------- init: V[j] = -||y_j||^2 ----------------
__global__ __launch_bounds__(256) void init_V(const float* __restrict__ y) {
    int wave = threadIdx.x >> 6;
    int lane = threadIdx.x & 63;
    int row = blockIdx.x * 4 + wave;
    const f32x4* yr = (const f32x4*)(y + (size_t)row * C);
    f32x4 v = yr[lane];
    float s = v.x * v.x + v.y * v.y + v.z * v.z + v.w * v.w;
    #pragma unroll
    for (int off = 32; off; off >>= 1) s += __shfl_down(s, off, 64);
    if (lane == 0) g_V[row] = -s;
}

// ---------------- GEMM: G = 2 * x @ y^T, quantized to int24 ----------------
#define GT 64
#define GKT 64
#define LSTR (GKT + 4)   // 68 floats; float4-aligned offsets

__global__ __launch_bounds__(256) void gemm_G(const float* __restrict__ x,
                                              const float* __restrict__ y,
                                              unsigned short* __restrict__ Glo,
                                              signed char* __restrict__ Ghi) {
    __shared__ float As[GT][LSTR];   // [i][k]
    __shared__ float Bs[GT][LSTR];   // [j][k]
    int bi = blockIdx.y * GT;
    int bj = blockIdx.x * GT;
    int t = threadIdx.x;
    int tx = t & 15, ty = t >> 4;
    float acc[4][4] = {};
    for (int kk = 0; kk < C; kk += GKT) {
        #pragma unroll
        for (int l = 0; l < 4; ++l) {
            int idx = t + l * 256;         // float4 index in tile
            int r = idx >> 4;              // tile row 0..63
            int c4 = idx & 15;             // float4 col 0..15
            *(f32x4*)&As[r][c4 * 4] =
                *(const f32x4*)(x + (size_t)(bi + r) * C + kk + c4 * 4);
            *(f32x4*)&Bs[r][c4 * 4] =
                *(const f32x4*)(y + (size_t)(bj + r) * C + kk + c4 * 4);
        }
        __syncthreads();
        #pragma unroll
        for (int k4 = 0; k4 < GKT / 4; ++k4) {
            f32x4 a[4], b[4];
            #pragma unroll
            for (int ii = 0; ii < 4; ++ii)
                a[ii] = *(const f32x4*)&As[ty * 4 + ii][k4 * 4];
            #pragma unroll
            for (int jj = 0; jj < 4; ++jj)
                b[jj] = *(const f32x4*)&Bs[tx + 16 * jj][k4 * 4];
            #pragma unroll
            for (int ii = 0; ii < 4; ++ii)
                #pragma unroll
                for (int jj = 0; jj < 4; ++jj) {
                    acc[ii][jj] = fmaf(a[ii].x, b[jj].x, acc[ii][jj]);
                    acc[ii][jj] = fmaf(a[ii].y, b[jj].y, acc[ii][jj]);
                    acc[ii][jj] = fmaf(a[ii].z, b[jj].z, acc[ii][jj]);
                    acc[ii][jj] = fmaf(a[ii].w, b[jj].w, acc[ii][jj]);
                }
        }
        __syncthreads();
    }
    #pragma unroll
    for (int ii = 0; ii < 4; ++ii) {
        int gi = bi + ty * 4 + ii;
        #pragma unroll
        for (int jj = 0; jj < 4; ++jj) {
            size_t idx = (size_t)gi * B + bj + tx + 16 * jj;
            float gs = acc[ii][jj] * QS;                       // G * 2^15
            gs = fminf(fmaxf(gs, -8388607.0f), 8388607.0f);    // int24 clamp
            int v = __float2int_rn(gs);
            Glo[idx] = (unsigned short)(v & 0xFFFF);
            Ghi[idx] = (signed char)(v >> 16);
        }
    }
}

// ---------------- row pass: U[i] = -LSE_j(G[i][j] + V[j]) ----------------
__global__ __launch_bounds__(256) void row_lse(const unsigned short* __restrict__ Glo,
                                               const signed char* __restrict__ Ghi) {
    int i = blockIdx.x;                     // ascending rows
    int t = threadIdx.x;
    const u16x8* lo8 = (const u16x8*)(Glo + (size_t)i * B);
    const i8x8*  hi8 = (const i8x8*)(Ghi + (size_t)i * B);
    const f32x4* v4 = (const f32x4*)g_V;
    float m = -INFINITY, s = 0.0f;
    #pragma unroll
    for (int it = 0; it < 4; ++it) {        // 8 j's per thread per iter
        int idx = it * 256 + t;             // 8-element chunk id
        u16x8 lo = lo8[idx];
        i8x8  hi = hi8[idx];
        f32x4 va = v4[idx * 2], vb = v4[idx * 2 + 1];
        float vv[8] = {va.x, va.y, va.z, va.w, vb.x, vb.y, vb.z, vb.w};
        #pragma unroll
        for (int k = 0; k < 8; ++k) {
            int q = ((int)hi[k] << 16) | (int)lo[k];
            float val = fmaf((float)q, QI, vv[k]);
            float m2 = fmaxf(m, val);
            s = s * __expf(m - m2) + __expf(val - m2);
            m = m2;
        }
    }
    __shared__ float sm[256], ss[256];
    sm[t] = m; ss[t] = s;
    __syncthreads();
    #pragma unroll
    for (int off = 128; off; off >>= 1) {
        if (t < off) {
            float mo = sm[t + off], so = ss[t + off];
            float m1 = sm[t],       s1 = ss[t];
            float m2 = fmaxf(m1, mo);
            ss[t] = s1 * __expf(m1 - m2) + so * __expf(mo - m2);
            sm[t] = m2;
        }
        __syncthreads();
    }
    if (t == 0) g_U[i] = -(sm[0] + logf(ss[0]));
}

// ------- column pass (partials): per (chunk, j): online LSE over 256 rows -------
// Zigzag: chunks and within-chunk rows walk DESCENDING so this pass starts
// on the rows row_lse touched last (MALL-freshest).
__global__ __launch_bounds__(256) void col_partial(const unsigned short* __restrict__ Glo,
                                                   const signed char* __restrict__ Ghi) {
    int t = threadIdx.x;
    int j = blockIdx.x * 256 + t;
    int chunk = (CHUNKS - 1) - blockIdx.y;
    int i0 = chunk * RPC;
    __shared__ float Us[RPC];
    Us[t] = g_U[i0 + t];
    __syncthreads();
    float m = -INFINITY, s = 0.0f;
    const unsigned short* lop = Glo + (size_t)i0 * B + j;
    const signed char*    hp  = Ghi + (size_t)i0 * B + j;
    #pragma unroll 8
    for (int r = RPC - 1; r >= 0; --r) {      // descending rows
        int q = ((int)hp[(size_t)r * B] << 16) | (int)lop[(size_t)r * B];
        float val = fmaf((float)q, QI, Us[r]);
        float m2 = fmaxf(m, val);
        s = s * __expf(m - m2) + __expf(val - m2);
        m = m2;
    }
    g_pm[chunk * B + j] = m;
    g_ps[chunk * B + j] = s;
}

// ---------------- column combine: V[j] = -(LSE of 32 partials) ----------------
__global__ __launch_bounds__(256) void col_combine() {
    int j = blockIdx.x * 256 + threadIdx.x;
    float m = -INFINITY, s = 0.0f;
    #pragma unroll
    for (int c = 0; c < CHUNKS; ++c) {
        float mc = g_pm[c * B + j], sc = g_ps[c * B + j];
        float m2 = fmaxf(m, mc);
        s = s * __expf(m - m2) + sc * __expf(mc - m2);
        m = m2;
    }
    g_V[j] = -(m + logf(s));
}

// ---------------- argmax + gather: out[i] = y[argmax_j(G[i][j]+V[j])] ----------------
__global__ __launch_bounds__(256) void argmax_out(const unsigned short* __restrict__ Glo,
                                                  const signed char* __restrict__ Ghi,
                                                  const float* __restrict__ y,
                                                  float* __restrict__ out) {
    int i = blockIdx.x;                      // ascending (last col pass ended low)
    int t = threadIdx.x;
    const u16x8* lo8 = (const u16x8*)(Glo + (size_t)i * B);
    const i8x8*  hi8 = (const i8x8*)(Ghi + (size_t)i * B);
    const f32x4* v4 = (const f32x4*)g_V;
    float best = -INFINITY;
    int bj = B;
    #pragma unroll
    for (int it = 0; it < 4; ++it) {
        int idx = it * 256 + t;
        u16x8 lo = lo8[idx];
        i8x8  hi = hi8[idx];
        f32x4 va = v4[idx * 2], vb = v4[idx * 2 + 1];
        float vv[8] = {va.x, va.y, va.z, va.w, vb.x, vb.y, vb.z, vb.w};
        #pragma unroll
        for (int k = 0; k < 8; ++k) {
            int q = ((int)hi[k] << 16) | (int)lo[k];
            float val = fmaf((float)q, QI, vv[k]);
            int j = idx * 8 + k;
            if (val > best) { best = val; bj = j; }
        }
    }
    __shared__ float bm[256];
    __shared__ int   bidx[256];
    bm[t] = best; bidx[t] = bj;
    __syncthreads();
    #pragma unroll
    for (int off = 128; off; off >>= 1) {
        if (t < off) {
            float om = bm[t + off]; int oj = bidx[t + off];
            if (om > bm[t] || (om == bm[t] && oj < bidx[t])) { bm[t] = om; bidx[t] = oj; }
        }
        __syncthreads();
    }
    int jstar = bidx[0];
    out[(size_t)i * C + t] = y[(size_t)jstar * C + t];
}

extern "C" void kernel_launch(void* const* d_in, const int* in_sizes, int n_in,
                              void* d_out, int out_size, void* d_ws, size_t ws_size,
                              hipStream_t stream) {
    const float* x = (const float*)d_in[0];
    const float* y = (const float*)d_in[1];
    float* out = (float*)d_out;
    unsigned short* Glo = (unsigned short*)d_ws;                       // 128 MiB
    signed char*    Ghi = (signed char*)((char*)d_ws + (size_t)B * B * 2); // +64 MiB

    init_V<<<B / 4, 256, 0, stream>>>(y);
    gemm_G<<<dim3(B / GT, B / GT), 256, 0, stream>>>(x, y, Glo, Ghi);
    for (int l = 0; l < LITERS; ++l) {
        row_lse<<<B, 256, 0, stream>>>(Glo, Ghi);
        col_partial<<<dim3(B / 256, CHUNKS), 256, 0, stream>>>(Glo, Ghi);
        col_combine<<<B / 256, 256, 0, stream>>>();
    }
    argmax_out<<<B, 256, 0, stream>>>(Glo, Ghi, y, out);
}